// Round 6
// baseline (583.038 us; speedup 1.0000x reference)
//
#include <hip/hip_runtime.h>
#include <math.h>

#define N_NODES 100000
#define N_EDGES 1600000

// ================= CSR build (by dst) =================

__global__ void k_count(const int* __restrict__ dst, int* __restrict__ cnt, int e) {
    int i = (blockIdx.x * blockDim.x + threadIdx.x) * 4;
    if (i + 3 < e) {
        int4 d4 = *(const int4*)(dst + i);
        atomicAdd(&cnt[d4.x], 1);
        atomicAdd(&cnt[d4.y], 1);
        atomicAdd(&cnt[d4.z], 1);
        atomicAdd(&cnt[d4.w], 1);
    } else {
        for (; i < e; ++i) atomicAdd(&cnt[dst[i]], 1);
    }
}

// scanA: per-block exclusive scan of 1024 ints (4/thread); block totals -> bsums.
// Also computes dinv = rsqrt(deg+1).
__global__ void k_scanA(const int* __restrict__ cnt, int* __restrict__ off,
                        int* __restrict__ bsums, float* __restrict__ dinv, int n) {
    __shared__ int sd[256];
    int t = threadIdx.x;
    int base = blockIdx.x * 1024 + t * 4;
    int e0 = (base + 0 < n) ? cnt[base + 0] : 0;
    int e1 = (base + 1 < n) ? cnt[base + 1] : 0;
    int e2 = (base + 2 < n) ? cnt[base + 2] : 0;
    int e3 = (base + 3 < n) ? cnt[base + 3] : 0;
    if (base + 0 < n) dinv[base + 0] = rsqrtf((float)e0 + 1.0f);
    if (base + 1 < n) dinv[base + 1] = rsqrtf((float)e1 + 1.0f);
    if (base + 2 < n) dinv[base + 2] = rsqrtf((float)e2 + 1.0f);
    if (base + 3 < n) dinv[base + 3] = rsqrtf((float)e3 + 1.0f);
    int s = e0 + e1 + e2 + e3;
    sd[t] = s;
    __syncthreads();
    for (int o = 1; o < 256; o <<= 1) {
        int v = (t >= o) ? sd[t - o] : 0;
        __syncthreads();
        sd[t] += v;
        __syncthreads();
    }
    int excl = sd[t] - s;
    if (base + 0 < n) off[base + 0] = excl;
    if (base + 1 < n) off[base + 1] = excl + e0;
    if (base + 2 < n) off[base + 2] = excl + e0 + e1;
    if (base + 3 < n) off[base + 3] = excl + e0 + e1 + e2;
    if (t == 0) bsums[blockIdx.x] = sd[255];
}

// scanC: every block redundantly scans bsums (nb<=128) in LDS, then applies the
// prefix to its 256 off entries; also initializes cursor. Absorbs former scanB.
__global__ void k_scanC(int* __restrict__ off, int* __restrict__ cursor,
                        const int* __restrict__ bsums, int nb, int n) {
    __shared__ int sd[128];
    int t = threadIdx.x;
    if (t < 128) sd[t] = (t < nb) ? bsums[t] : 0;
    __syncthreads();
    for (int o = 1; o < 128; o <<= 1) {
        int v = (t >= o && t < 128) ? sd[t - o] : 0;
        __syncthreads();
        if (t < 128) sd[t] += v;
        __syncthreads();
    }
    int i = blockIdx.x * 256 + t;
    if (i < n) {
        int b = i >> 10;
        int add = (b == 0) ? 0 : sd[b - 1];
        int v = off[i] + add;
        off[i] = v;
        cursor[i] = v;
    }
    if (blockIdx.x == 0 && t == 0) off[n] = sd[nb - 1];
}

__global__ void k_fill(const int* __restrict__ src, const int* __restrict__ dst,
                       int* __restrict__ cursor, int* __restrict__ csr, int e) {
    int i = (blockIdx.x * blockDim.x + threadIdx.x) * 4;
    if (i + 3 < e) {
        int4 s4 = *(const int4*)(src + i);
        int4 d4 = *(const int4*)(dst + i);
        csr[atomicAdd(&cursor[d4.x], 1)] = s4.x;
        csr[atomicAdd(&cursor[d4.y], 1)] = s4.y;
        csr[atomicAdd(&cursor[d4.z], 1)] = s4.z;
        csr[atomicAdd(&cursor[d4.w], 1)] = s4.w;
    } else {
        for (; i < e; ++i) csr[atomicAdd(&cursor[dst[i]], 1)] = src[i];
    }
}

// ======== fold: xs[s][f] = x[s][f] * dinv[s] (fp32, 256-B rows) ========
// grid covers n*16 float4s exactly (100000*16/256 = 6250 blocks).

__global__ void k_fold(const float* __restrict__ x, const float* __restrict__ dinv,
                       float* __restrict__ xs) {
    int t = blockIdx.x * blockDim.x + threadIdx.x;  // float4 index
    float4 v = ((const float4*)x)[t];
    float di = dinv[t >> 4];
    float4 o;
    o.x = v.x * di; o.y = v.y * di; o.z = v.z * di; o.w = v.w * di;
    ((float4*)xs)[t] = o;
}

// ======== Fused layer-1 agg + GEMM1 + relu + GEMM2: h2s = relu((A_hat X)W1+b1)@W2 * dinv ========
// 4 waves/block, 4 nodes/wave (16/block; grid 6250 exact).
// Gather: lane = 16*G + c4. Per instr: 4 rows (edges) x 16 lanes x float4 = 4x256B,
// 16-edge unroll = 16 rows in flight, inner op = bare float4 add (dinv prefolded).
// Remainder: looped 4-at-a-time cleanup covers ALL leftovers (R5 bug: fixed).
// Phase B (W1 in LDS) and C (W2 in LDS, padded) are wave-local, no extra barriers.

__global__ __launch_bounds__(256, 7) void k_agg1(
        const float* __restrict__ xs, const int* __restrict__ off,
        const int* __restrict__ csr, const float* __restrict__ dinv,
        const float* __restrict__ W1, const float* __restrict__ W2,
        const float* __restrict__ b1, float* __restrict__ h2s, int n) {
    __shared__ float W1s[64 * 64];
    __shared__ float W2s[64 * 17];   // padded
    __shared__ float xsw[4][64];
    __shared__ float vsw[4][64];
    int tid = threadIdx.x;
    {
        const float4* W14 = (const float4*)W1;
        float4* W1s4 = (float4*)W1s;
#pragma unroll
        for (int i = 0; i < 4; ++i) W1s4[tid + 256 * i] = W14[tid + 256 * i];
        for (int i = tid; i < 64 * 16; i += 256) W2s[(i >> 4) * 17 + (i & 15)] = W2[i];
    }
    __syncthreads();  // only block-wide barrier

    int w = tid >> 6, lane = tid & 63;
    int G = lane >> 4;        // edge slot 0..3
    int c4 = lane & 15;       // float4 column
    int f = lane;
    float b1f = b1[f];
    const float4* x4 = (const float4*)xs;

    int base = blockIdx.x * 16 + w * 4;
#pragma unroll 1
    for (int nn = 0; nn < 4; ++nn) {
        int d = base + nn;    // grid covers n exactly
        float dd = dinv[d];
        float4 aA, aB, aC, aD;
        if (G == 0) aA = x4[(size_t)d * 16 + c4];   // self term (prefolded)
        else        { aA.x = 0.f; aA.y = 0.f; aA.z = 0.f; aA.w = 0.f; }
        aB.x = 0.f; aB.y = 0.f; aB.z = 0.f; aB.w = 0.f;
        aC = aB; aD = aB;
        int j = off[d], je = off[d + 1];
        for (; j + 16 <= je; j += 16) {
            int sA = csr[j + G], sB = csr[j + 4 + G];
            int sC = csr[j + 8 + G], sD = csr[j + 12 + G];
            float4 vA = x4[(size_t)sA * 16 + c4];
            float4 vB = x4[(size_t)sB * 16 + c4];
            float4 vC = x4[(size_t)sC * 16 + c4];
            float4 vD = x4[(size_t)sD * 16 + c4];
            aA.x += vA.x; aA.y += vA.y; aA.z += vA.z; aA.w += vA.w;
            aB.x += vB.x; aB.y += vB.y; aB.z += vB.z; aB.w += vB.w;
            aC.x += vC.x; aC.y += vC.y; aC.z += vC.z; aC.w += vC.w;
            aD.x += vD.x; aD.y += vD.y; aD.z += vD.z; aD.w += vD.w;
        }
        for (; j + 8 <= je; j += 8) {
            int sA = csr[j + G], sB = csr[j + 4 + G];
            float4 vA = x4[(size_t)sA * 16 + c4];
            float4 vB = x4[(size_t)sB * 16 + c4];
            aA.x += vA.x; aA.y += vA.y; aA.z += vA.z; aA.w += vA.w;
            aB.x += vB.x; aB.y += vB.y; aB.z += vB.z; aB.w += vB.w;
        }
        for (; j < je; j += 4) {   // covers rem 0..7 fully (<=2 iterations)
            if (j + G < je) {
                int sA = csr[j + G];
                float4 vA = x4[(size_t)sA * 16 + c4];
                aA.x += vA.x; aA.y += vA.y; aA.z += vA.z; aA.w += vA.w;
            }
        }
        aA.x += aB.x + aC.x + aD.x;
        aA.y += aB.y + aC.y + aD.y;
        aA.z += aB.z + aC.z + aD.z;
        aA.w += aB.w + aC.w + aD.w;
        aA.x += __shfl_xor(aA.x, 16); aA.x += __shfl_xor(aA.x, 32);
        aA.y += __shfl_xor(aA.y, 16); aA.y += __shfl_xor(aA.y, 32);
        aA.z += __shfl_xor(aA.z, 16); aA.z += __shfl_xor(aA.z, 32);
        aA.w += __shfl_xor(aA.w, 16); aA.w += __shfl_xor(aA.w, 32);
        if (G == 0) {
            float4 o;
            o.x = aA.x * dd; o.y = aA.y * dd; o.z = aA.z * dd; o.w = aA.w * dd;
            ((float4*)xsw[w])[c4] = o;
        }
        // Phase B: out1[f] = b1[f] + sum_k agg[k]*W1[k][f]; relu
        float accF = b1f;
        const float4* xw4 = (const float4*)xsw[w];
#pragma unroll
        for (int k4 = 0; k4 < 16; ++k4) {
            float4 xv = xw4[k4];
            accF = fmaf(xv.x, W1s[(k4 * 4 + 0) * 64 + f], accF);
            accF = fmaf(xv.y, W1s[(k4 * 4 + 1) * 64 + f], accF);
            accF = fmaf(xv.z, W1s[(k4 * 4 + 2) * 64 + f], accF);
            accF = fmaf(xv.w, W1s[(k4 * 4 + 3) * 64 + f], accF);
        }
        vsw[w][f] = fmaxf(accF, 0.f);
        // Phase C: h2s[d][c] = (sum_k v[k]*W2[k][c]) * dd   (dinv prefolded for agg2)
        float p = 0.f;
        const float4* vw4 = (const float4*)vsw[w];
#pragma unroll
        for (int kk4 = 0; kk4 < 4; ++kk4) {
            float4 vv = vw4[G * 4 + kk4];
            p = fmaf(vv.x, W2s[(G * 16 + kk4 * 4 + 0) * 17 + c4], p);
            p = fmaf(vv.y, W2s[(G * 16 + kk4 * 4 + 1) * 17 + c4], p);
            p = fmaf(vv.z, W2s[(G * 16 + kk4 * 4 + 2) * 17 + c4], p);
            p = fmaf(vv.w, W2s[(G * 16 + kk4 * 4 + 3) * 17 + c4], p);
        }
        p += __shfl_xor(p, 16);
        p += __shfl_xor(p, 32);
        if (G == 0) h2s[(size_t)d * 16 + c4] = p * dd;
    }
}

// ======== Layer-2 aggregation + b2 + log_softmax ========
// 1 node/wave, 4 waves/block (grid 25000 exact). lane = 4*r + c4:
// r = edge slot (16 edges in flight per load instr), c4 = float4 of the 16-f row.
// Inner op = bare float4 add (dinv prefolded into h2s).

__global__ __launch_bounds__(256, 8) void k_agg2_lsm(
        const float* __restrict__ h2s, const int* __restrict__ off,
        const int* __restrict__ csr, const float* __restrict__ dinv,
        const float* __restrict__ b2, float* __restrict__ y, int n) {
    int tid = threadIdx.x;
    int w = tid >> 6, lane = tid & 63;
    int r = lane >> 2;    // 0..15 edge slot
    int c4 = lane & 3;    // float4 col
    int d = blockIdx.x * 4 + w;   // grid covers n exactly
    const float4* h4 = (const float4*)h2s;
    float4 b24 = ((const float4*)b2)[c4];
    float dd = dinv[d];
    float4 acc;
    if (r == 0) acc = h4[(size_t)d * 4 + c4];  // self (prefolded)
    else        { acc.x = 0.f; acc.y = 0.f; acc.z = 0.f; acc.w = 0.f; }
    int j = off[d], je = off[d + 1];
    for (; j + 16 <= je; j += 16) {
        int s = csr[j + r];
        float4 v = h4[(size_t)s * 4 + c4];
        acc.x += v.x; acc.y += v.y; acc.z += v.z; acc.w += v.w;
    }
    if (j < je) {
        if (j + r < je) {   // rem < 16: 16 slots cover it fully
            int s = csr[j + r];
            float4 v = h4[(size_t)s * 4 + c4];
            acc.x += v.x; acc.y += v.y; acc.z += v.z; acc.w += v.w;
        }
    }
#pragma unroll
    for (int o = 4; o < 64; o <<= 1) {
        acc.x += __shfl_xor(acc.x, o);
        acc.y += __shfl_xor(acc.y, o);
        acc.z += __shfl_xor(acc.z, o);
        acc.w += __shfl_xor(acc.w, o);
    }
    float4 v4;
    v4.x = acc.x * dd + b24.x;
    v4.y = acc.y * dd + b24.y;
    v4.z = acc.z * dd + b24.z;
    v4.w = acc.w * dd + b24.w;
    float m = fmaxf(fmaxf(v4.x, v4.y), fmaxf(v4.z, v4.w));
    m = fmaxf(m, __shfl_xor(m, 1));
    m = fmaxf(m, __shfl_xor(m, 2));
    float ss = expf(v4.x - m) + expf(v4.y - m) + expf(v4.z - m) + expf(v4.w - m);
    ss += __shfl_xor(ss, 1);
    ss += __shfl_xor(ss, 2);
    float lse = logf(ss) + m;
    if (r == 0) {
        float4 o;
        o.x = v4.x - lse; o.y = v4.y - lse; o.z = v4.z - lse; o.w = v4.w - lse;
        ((float4*)y)[(size_t)d * 4 + c4] = o;
    }
}

// ================= launcher =================

extern "C" void kernel_launch(void* const* d_in, const int* in_sizes, int n_in,
                              void* d_out, int out_size, void* d_ws, size_t ws_size,
                              hipStream_t stream) {
    const float* x  = (const float*)d_in[0];
    const int*   ei = (const int*)d_in[1];          // [2, E] row-major
    const float* W1 = (const float*)d_in[2];
    const float* b1 = (const float*)d_in[3];
    const float* W2 = (const float*)d_in[4];
    const float* b2 = (const float*)d_in[5];
    float* y = (float*)d_out;

    const int n = N_NODES;
    const int e = N_EDGES;
    const int* src = ei;
    const int* dst = ei + e;

    // workspace layout (4-byte units); total ~40 MB
    float* ws = (float*)d_ws;
    int*   cnt    = (int*)ws;                   // n
    float* dinv   = ws + 102400;                // n
    int*   off    = (int*)(ws + 204800);        // n+1
    int*   cursor = (int*)(ws + 307200);        // n
    int*   bsums  = (int*)(ws + 409600);        // <=128
    int*   csr    = (int*)(ws + 410624);        // e
    float* xs     = ws + 2010624;               // n*64 (25.6MB), 16B-aligned
    float* h2s    = ws + 8410624;               // n*16

    const int nb = (n + 1023) / 1024;           // 98

    hipMemsetAsync(cnt, 0, (size_t)n * sizeof(int), stream);
    k_count<<<(e / 4 + 255) / 256, 256, 0, stream>>>(dst, cnt, e);
    k_scanA<<<nb, 256, 0, stream>>>(cnt, off, bsums, dinv, n);
    k_fold <<<n * 16 / 256, 256, 0, stream>>>(x, dinv, xs);          // 6250
    k_scanC<<<(n + 255) / 256, 256, 0, stream>>>(off, cursor, bsums, nb, n);
    k_fill <<<(e / 4 + 255) / 256, 256, 0, stream>>>(src, dst, cursor, csr, e);

    k_agg1    <<<n / 16, 256, 0, stream>>>(xs, off, csr, dinv, W1, W2, b1, h2s, n);  // 6250
    k_agg2_lsm<<<n / 4, 256, 0, stream>>>(h2s, off, csr, dinv, b2, y, n);            // 25000
}

// Round 7
// 376.145 us; speedup vs baseline: 1.5500x; 1.5500x over previous
//
#include <hip/hip_runtime.h>
#include <math.h>

#define N_NODES 100000
#define N_EDGES 1600000

// ================= CSR build (by dst) =================

__global__ void k_count(const int* __restrict__ dst, int* __restrict__ cnt, int e) {
    int i = (blockIdx.x * blockDim.x + threadIdx.x) * 4;
    if (i + 3 < e) {
        int4 d4 = *(const int4*)(dst + i);
        atomicAdd(&cnt[d4.x], 1);
        atomicAdd(&cnt[d4.y], 1);
        atomicAdd(&cnt[d4.z], 1);
        atomicAdd(&cnt[d4.w], 1);
    } else {
        for (; i < e; ++i) atomicAdd(&cnt[dst[i]], 1);
    }
}

// scanA: per-block exclusive scan of 1024 ints (4/thread); block totals -> bsums.
// Also computes dinv = rsqrt(deg+1).
__global__ void k_scanA(const int* __restrict__ cnt, int* __restrict__ off,
                        int* __restrict__ bsums, float* __restrict__ dinv, int n) {
    __shared__ int sd[256];
    int t = threadIdx.x;
    int base = blockIdx.x * 1024 + t * 4;
    int e0 = (base + 0 < n) ? cnt[base + 0] : 0;
    int e1 = (base + 1 < n) ? cnt[base + 1] : 0;
    int e2 = (base + 2 < n) ? cnt[base + 2] : 0;
    int e3 = (base + 3 < n) ? cnt[base + 3] : 0;
    if (base + 0 < n) dinv[base + 0] = rsqrtf((float)e0 + 1.0f);
    if (base + 1 < n) dinv[base + 1] = rsqrtf((float)e1 + 1.0f);
    if (base + 2 < n) dinv[base + 2] = rsqrtf((float)e2 + 1.0f);
    if (base + 3 < n) dinv[base + 3] = rsqrtf((float)e3 + 1.0f);
    int s = e0 + e1 + e2 + e3;
    sd[t] = s;
    __syncthreads();
    for (int o = 1; o < 256; o <<= 1) {
        int v = (t >= o) ? sd[t - o] : 0;
        __syncthreads();
        sd[t] += v;
        __syncthreads();
    }
    int excl = sd[t] - s;
    if (base + 0 < n) off[base + 0] = excl;
    if (base + 1 < n) off[base + 1] = excl + e0;
    if (base + 2 < n) off[base + 2] = excl + e0 + e1;
    if (base + 3 < n) off[base + 3] = excl + e0 + e1 + e2;
    if (t == 0) bsums[blockIdx.x] = sd[255];
}

// scanC: every block redundantly scans bsums (nb<=128) in LDS, then applies the
// prefix to its 256 off entries; also initializes cursor.
__global__ void k_scanC(int* __restrict__ off, int* __restrict__ cursor,
                        const int* __restrict__ bsums, int nb, int n) {
    __shared__ int sd[128];
    int t = threadIdx.x;
    if (t < 128) sd[t] = (t < nb) ? bsums[t] : 0;
    __syncthreads();
    for (int o = 1; o < 128; o <<= 1) {
        int v = (t >= o && t < 128) ? sd[t - o] : 0;
        __syncthreads();
        if (t < 128) sd[t] += v;
        __syncthreads();
    }
    int i = blockIdx.x * 256 + t;
    if (i < n) {
        int b = i >> 10;
        int add = (b == 0) ? 0 : sd[b - 1];
        int v = off[i] + add;
        off[i] = v;
        cursor[i] = v;
    }
    if (blockIdx.x == 0 && t == 0) off[n] = sd[nb - 1];
}

__global__ void k_fill(const int* __restrict__ src, const int* __restrict__ dst,
                       int* __restrict__ cursor, int* __restrict__ csr, int e) {
    int i = (blockIdx.x * blockDim.x + threadIdx.x) * 4;
    if (i + 3 < e) {
        int4 s4 = *(const int4*)(src + i);
        int4 d4 = *(const int4*)(dst + i);
        csr[atomicAdd(&cursor[d4.x], 1)] = s4.x;
        csr[atomicAdd(&cursor[d4.y], 1)] = s4.y;
        csr[atomicAdd(&cursor[d4.z], 1)] = s4.z;
        csr[atomicAdd(&cursor[d4.w], 1)] = s4.w;
    } else {
        for (; i < e; ++i) csr[atomicAdd(&cursor[dst[i]], 1)] = src[i];
    }
}

// ======== fold: xs[s][f] = x[s][f] * dinv[s] ========
__global__ void k_fold(const float* __restrict__ x, const float* __restrict__ dinv,
                       float* __restrict__ xs) {
    int t = blockIdx.x * blockDim.x + threadIdx.x;  // float4 index
    float4 v = ((const float4*)x)[t];
    float di = dinv[t >> 4];
    float4 o;
    o.x = v.x * di; o.y = v.y * di; o.z = v.z * di; o.w = v.w * di;
    ((float4*)xs)[t] = o;
}

// ======== Fused layer-1 agg + GEMM1 + relu + GEMM2 ========
// 4 waves/block, 4 nodes/wave sequential (16/block; grid 6250 exact).
// Gather shape = R1's proven-clean pattern: lane = feature f; ONE full-wave
// contiguous 256B row per load instruction; csr index wave-uniform (scalar);
// 4 independent accumulator chains (shallow in-flight; MLP from occupancy).
// Inner op = bare add (dinv prefolded into xs).

__global__ void k_agg1(
        const float* __restrict__ xs, const int* __restrict__ off,
        const int* __restrict__ csr, const float* __restrict__ dinv,
        const float* __restrict__ W1, const float* __restrict__ W2,
        const float* __restrict__ b1, float* __restrict__ h2s, int n) {
    __shared__ float W1s[64 * 64];
    __shared__ float W2s[64 * 17];   // padded
    __shared__ float xsw[4][64];
    __shared__ float vsw[4][64];
    int tid = threadIdx.x;
    {
        const float4* W14 = (const float4*)W1;
        float4* W1s4 = (float4*)W1s;
#pragma unroll
        for (int i = 0; i < 4; ++i) W1s4[tid + 256 * i] = W14[tid + 256 * i];
        for (int i = tid; i < 64 * 16; i += 256) W2s[(i >> 4) * 17 + (i & 15)] = W2[i];
    }
    __syncthreads();  // only block-wide barrier

    int w = tid >> 6, lane = tid & 63;
    int f = lane;
    int G = lane >> 4;        // used in phase C
    int c4 = lane & 15;
    float b1f = b1[f];

    int base = blockIdx.x * 16 + w * 4;
#pragma unroll 1
    for (int nn = 0; nn < 4; ++nn) {
        int d = base + nn;    // grid covers n exactly
        float dd = dinv[d];
        // self term: out1 = dd*(sum_j xs[s_j] + xs[d])  (xs prefolded by dinv[src])
        float a0 = xs[(size_t)d * 64 + f];
        float a1 = 0.f, a2 = 0.f, a3 = 0.f;
        int j = off[d], je = off[d + 1];
        for (; j + 4 <= je; j += 4) {
            int s0 = csr[j + 0], s1 = csr[j + 1];   // wave-uniform scalar loads
            int s2 = csr[j + 2], s3 = csr[j + 3];
            a0 += xs[(size_t)s0 * 64 + f];          // full-wave 256B row each
            a1 += xs[(size_t)s1 * 64 + f];
            a2 += xs[(size_t)s2 * 64 + f];
            a3 += xs[(size_t)s3 * 64 + f];
        }
        for (; j < je; ++j) {
            int s0 = csr[j];
            a0 += xs[(size_t)s0 * 64 + f];
        }
        xsw[w][f] = ((a0 + a1) + (a2 + a3)) * dd;   // same-wave producer
        // Phase B: out1[f] = b1[f] + sum_k agg[k]*W1[k][f]; relu
        float accF = b1f;
        const float4* xw4 = (const float4*)xsw[w];
#pragma unroll
        for (int k4 = 0; k4 < 16; ++k4) {
            float4 xv = xw4[k4];
            accF = fmaf(xv.x, W1s[(k4 * 4 + 0) * 64 + f], accF);
            accF = fmaf(xv.y, W1s[(k4 * 4 + 1) * 64 + f], accF);
            accF = fmaf(xv.z, W1s[(k4 * 4 + 2) * 64 + f], accF);
            accF = fmaf(xv.w, W1s[(k4 * 4 + 3) * 64 + f], accF);
        }
        vsw[w][f] = fmaxf(accF, 0.f);
        // Phase C: h2s[d][c] = (sum_k v[k]*W2[k][c]) * dd  (prefold dd for agg2)
        float p = 0.f;
        const float4* vw4 = (const float4*)vsw[w];
#pragma unroll
        for (int kk4 = 0; kk4 < 4; ++kk4) {
            float4 vv = vw4[G * 4 + kk4];
            p = fmaf(vv.x, W2s[(G * 16 + kk4 * 4 + 0) * 17 + c4], p);
            p = fmaf(vv.y, W2s[(G * 16 + kk4 * 4 + 1) * 17 + c4], p);
            p = fmaf(vv.z, W2s[(G * 16 + kk4 * 4 + 2) * 17 + c4], p);
            p = fmaf(vv.w, W2s[(G * 16 + kk4 * 4 + 3) * 17 + c4], p);
        }
        p += __shfl_xor(p, 16);
        p += __shfl_xor(p, 32);
        if (G == 0) h2s[(size_t)d * 16 + c4] = p * dd;
    }
}

// ======== Layer-2 aggregation + b2 + log_softmax ========
// 1 node/wave, 4 waves/block (grid 25000 exact). lane = 16*g + c:
// g = edge slot (4 rows x 64B per instruction), c = feature. Depth 2.
// Inner op = bare add (dinv prefolded into h2s).

__global__ void k_agg2_lsm(
        const float* __restrict__ h2s, const int* __restrict__ off,
        const int* __restrict__ csr, const float* __restrict__ dinv,
        const float* __restrict__ b2, float* __restrict__ y, int n) {
    int tid = threadIdx.x;
    int w = tid >> 6, lane = tid & 63, g = lane >> 4, c = lane & 15;
    int d = blockIdx.x * 4 + w;   // grid covers n exactly
    float dd = dinv[d];
    float acc0 = (g == 0) ? h2s[(size_t)d * 16 + c] : 0.f;  // self (prefolded)
    float acc1 = 0.f;
    int j = off[d], je = off[d + 1];
    for (; j + 8 <= je; j += 8) {
        int sA = csr[j + g], sB = csr[j + 4 + g];
        acc0 += h2s[(size_t)sA * 16 + c];
        acc1 += h2s[(size_t)sB * 16 + c];
    }
    for (; j < je; j += 4) {          // covers rem 0..7 fully (<=2 iterations)
        if (j + g < je) {
            int s = csr[j + g];
            acc0 += h2s[(size_t)s * 16 + c];
        }
    }
    float acc = acc0 + acc1;
    acc += __shfl_xor(acc, 16);
    acc += __shfl_xor(acc, 32);
    float v = acc * dd + b2[c];
    float m = v;
#pragma unroll
    for (int o = 1; o < 16; o <<= 1) m = fmaxf(m, __shfl_xor(m, o));
    float ss = expf(v - m);
#pragma unroll
    for (int o = 1; o < 16; o <<= 1) ss += __shfl_xor(ss, o);
    float lse = logf(ss) + m;
    if (g == 0) y[(size_t)d * 16 + c] = v - lse;
}

// ================= launcher =================

extern "C" void kernel_launch(void* const* d_in, const int* in_sizes, int n_in,
                              void* d_out, int out_size, void* d_ws, size_t ws_size,
                              hipStream_t stream) {
    const float* x  = (const float*)d_in[0];
    const int*   ei = (const int*)d_in[1];          // [2, E] row-major
    const float* W1 = (const float*)d_in[2];
    const float* b1 = (const float*)d_in[3];
    const float* W2 = (const float*)d_in[4];
    const float* b2 = (const float*)d_in[5];
    float* y = (float*)d_out;

    const int n = N_NODES;
    const int e = N_EDGES;
    const int* src = ei;
    const int* dst = ei + e;

    // workspace layout (4-byte units); total ~40 MB
    float* ws = (float*)d_ws;
    int*   cnt    = (int*)ws;                   // n
    float* dinv   = ws + 102400;                // n
    int*   off    = (int*)(ws + 204800);        // n+1
    int*   cursor = (int*)(ws + 307200);        // n
    int*   bsums  = (int*)(ws + 409600);        // <=128
    int*   csr    = (int*)(ws + 410624);        // e
    float* xs     = ws + 2010624;               // n*64 (25.6MB), 16B-aligned
    float* h2s    = ws + 8410624;               // n*16

    const int nb = (n + 1023) / 1024;           // 98

    hipMemsetAsync(cnt, 0, (size_t)n * sizeof(int), stream);
    k_count<<<(e / 4 + 255) / 256, 256, 0, stream>>>(dst, cnt, e);
    k_scanA<<<nb, 256, 0, stream>>>(cnt, off, bsums, dinv, n);
    k_fold <<<n * 16 / 256, 256, 0, stream>>>(x, dinv, xs);          // 6250
    k_scanC<<<(n + 255) / 256, 256, 0, stream>>>(off, cursor, bsums, nb, n);
    k_fill <<<(e / 4 + 255) / 256, 256, 0, stream>>>(src, dst, cursor, csr, e);

    k_agg1    <<<n / 16, 256, 0, stream>>>(xs, off, csr, dinv, W1, W2, b1, h2s, n);  // 6250
    k_agg2_lsm<<<n / 4, 256, 0, stream>>>(h2s, off, csr, dinv, b2, y, n);            // 25000
}

// Round 8
// 360.839 us; speedup vs baseline: 1.6158x; 1.0424x over previous
//
#include <hip/hip_runtime.h>
#include <hip/hip_fp16.h>
#include <math.h>

#define N_NODES 100000
#define N_EDGES 1600000

// ================= CSR build (by dst) =================

__global__ void k_count(const int* __restrict__ dst, int* __restrict__ cnt, int e) {
    int i = (blockIdx.x * blockDim.x + threadIdx.x) * 4;
    if (i + 3 < e) {
        int4 d4 = *(const int4*)(dst + i);
        atomicAdd(&cnt[d4.x], 1);
        atomicAdd(&cnt[d4.y], 1);
        atomicAdd(&cnt[d4.z], 1);
        atomicAdd(&cnt[d4.w], 1);
    } else {
        for (; i < e; ++i) atomicAdd(&cnt[dst[i]], 1);
    }
}

// scanA: per-block exclusive scan of 1024 ints (4/thread); block totals -> bsums.
// Also computes dinv = rsqrt(deg+1).
__global__ void k_scanA(const int* __restrict__ cnt, int* __restrict__ off,
                        int* __restrict__ bsums, float* __restrict__ dinv, int n) {
    __shared__ int sd[256];
    int t = threadIdx.x;
    int base = blockIdx.x * 1024 + t * 4;
    int e0 = (base + 0 < n) ? cnt[base + 0] : 0;
    int e1 = (base + 1 < n) ? cnt[base + 1] : 0;
    int e2 = (base + 2 < n) ? cnt[base + 2] : 0;
    int e3 = (base + 3 < n) ? cnt[base + 3] : 0;
    if (base + 0 < n) dinv[base + 0] = rsqrtf((float)e0 + 1.0f);
    if (base + 1 < n) dinv[base + 1] = rsqrtf((float)e1 + 1.0f);
    if (base + 2 < n) dinv[base + 2] = rsqrtf((float)e2 + 1.0f);
    if (base + 3 < n) dinv[base + 3] = rsqrtf((float)e3 + 1.0f);
    int s = e0 + e1 + e2 + e3;
    sd[t] = s;
    __syncthreads();
    for (int o = 1; o < 256; o <<= 1) {
        int v = (t >= o) ? sd[t - o] : 0;
        __syncthreads();
        sd[t] += v;
        __syncthreads();
    }
    int excl = sd[t] - s;
    if (base + 0 < n) off[base + 0] = excl;
    if (base + 1 < n) off[base + 1] = excl + e0;
    if (base + 2 < n) off[base + 2] = excl + e0 + e1;
    if (base + 3 < n) off[base + 3] = excl + e0 + e1 + e2;
    if (t == 0) bsums[blockIdx.x] = sd[255];
}

// scanC: every block redundantly scans bsums (nb<=128) in LDS, then applies the
// prefix to its 256 off entries; also initializes cursor.
__global__ void k_scanC(int* __restrict__ off, int* __restrict__ cursor,
                        const int* __restrict__ bsums, int nb, int n) {
    __shared__ int sd[128];
    int t = threadIdx.x;
    if (t < 128) sd[t] = (t < nb) ? bsums[t] : 0;
    __syncthreads();
    for (int o = 1; o < 128; o <<= 1) {
        int v = (t >= o && t < 128) ? sd[t - o] : 0;
        __syncthreads();
        if (t < 128) sd[t] += v;
        __syncthreads();
    }
    int i = blockIdx.x * 256 + t;
    if (i < n) {
        int b = i >> 10;
        int add = (b == 0) ? 0 : sd[b - 1];
        int v = off[i] + add;
        off[i] = v;
        cursor[i] = v;
    }
    if (blockIdx.x == 0 && t == 0) off[n] = sd[nb - 1];
}

__global__ void k_fill(const int* __restrict__ src, const int* __restrict__ dst,
                       int* __restrict__ cursor, int* __restrict__ csr, int e) {
    int i = (blockIdx.x * blockDim.x + threadIdx.x) * 4;
    if (i + 3 < e) {
        int4 s4 = *(const int4*)(src + i);
        int4 d4 = *(const int4*)(dst + i);
        csr[atomicAdd(&cursor[d4.x], 1)] = s4.x;
        csr[atomicAdd(&cursor[d4.y], 1)] = s4.y;
        csr[atomicAdd(&cursor[d4.z], 1)] = s4.z;
        csr[atomicAdd(&cursor[d4.w], 1)] = s4.w;
    } else {
        for (; i < e; ++i) csr[atomicAdd(&cursor[dst[i]], 1)] = src[i];
    }
}

// ======== fold: xs[s][f] = x[s][f] * dinv[s] ========
__global__ void k_fold(const float* __restrict__ x, const float* __restrict__ dinv,
                       float* __restrict__ xs) {
    int t = blockIdx.x * blockDim.x + threadIdx.x;  // float4 index
    float4 v = ((const float4*)x)[t];
    float di = dinv[t >> 4];
    float4 o;
    o.x = v.x * di; o.y = v.y * di; o.z = v.z * di; o.w = v.w * di;
    ((float4*)xs)[t] = o;
}

// ======== Fused layer-1 agg + GEMM1 + relu + GEMM2 ========
// 4 waves/block, 4 nodes/wave sequential (16/block; grid 6250 exact).
// Gather: lane = feature f; ONE full-wave contiguous 256B row per load instr
// (the proven-clean shape); csr indices wave-uniform scalar loads, software-
// prefetched one iteration ahead so next iteration's row loads issue without
// waiting on the s_load chain. Inner op = bare add (dinv prefolded into xs).
// Output h2s stored as fp16 (3.2MB -> L2-resident for agg2).

__global__ void k_agg1(
        const float* __restrict__ xs, const int* __restrict__ off,
        const int* __restrict__ csr, const float* __restrict__ dinv,
        const float* __restrict__ W1, const float* __restrict__ W2,
        const float* __restrict__ b1, __half* __restrict__ h2h, int n) {
    __shared__ float W1s[64 * 64];
    __shared__ float W2s[64 * 17];   // padded
    __shared__ float xsw[4][64];
    __shared__ float vsw[4][64];
    int tid = threadIdx.x;
    {
        const float4* W14 = (const float4*)W1;
        float4* W1s4 = (float4*)W1s;
#pragma unroll
        for (int i = 0; i < 4; ++i) W1s4[tid + 256 * i] = W14[tid + 256 * i];
        for (int i = tid; i < 64 * 16; i += 256) W2s[(i >> 4) * 17 + (i & 15)] = W2[i];
    }
    __syncthreads();  // only block-wide barrier

    int w = tid >> 6, lane = tid & 63;
    int f = lane;
    int G = lane >> 4;        // used in phase C
    int c4 = lane & 15;
    float b1f = b1[f];

    int base = blockIdx.x * 16 + w * 4;
#pragma unroll 1
    for (int nn = 0; nn < 4; ++nn) {
        int d = base + nn;    // grid covers n exactly
        float dd = dinv[d];
        float a0 = xs[(size_t)d * 64 + f];   // self term (prefolded)
        float a1 = 0.f, a2 = 0.f, a3 = 0.f;
        int j = off[d], je = off[d + 1];
        // software-pipelined 4-wide gather: prefetch next 4 csr indices
        int s0 = 0, s1 = 0, s2 = 0, s3 = 0;
        if (j + 4 <= je) { s0 = csr[j]; s1 = csr[j + 1]; s2 = csr[j + 2]; s3 = csr[j + 3]; }
        while (j + 4 <= je) {
            int t0 = s0, t1 = s1, t2 = s2, t3 = s3;
            if (j + 8 <= je) { t0 = csr[j + 4]; t1 = csr[j + 5]; t2 = csr[j + 6]; t3 = csr[j + 7]; }
            a0 += xs[(size_t)s0 * 64 + f];
            a1 += xs[(size_t)s1 * 64 + f];
            a2 += xs[(size_t)s2 * 64 + f];
            a3 += xs[(size_t)s3 * 64 + f];
            s0 = t0; s1 = t1; s2 = t2; s3 = t3;
            j += 4;
        }
        for (; j < je; ++j) {
            int s = csr[j];
            a0 += xs[(size_t)s * 64 + f];
        }
        xsw[w][f] = ((a0 + a1) + (a2 + a3)) * dd;   // same-wave producer
        // Phase B: out1[f] = b1[f] + sum_k agg[k]*W1[k][f]; relu (4 partial chains)
        float p0 = b1f, p1 = 0.f, p2 = 0.f, p3 = 0.f;
        const float4* xw4 = (const float4*)xsw[w];
#pragma unroll
        for (int k4 = 0; k4 < 16; ++k4) {
            float4 xv = xw4[k4];
            p0 = fmaf(xv.x, W1s[(k4 * 4 + 0) * 64 + f], p0);
            p1 = fmaf(xv.y, W1s[(k4 * 4 + 1) * 64 + f], p1);
            p2 = fmaf(xv.z, W1s[(k4 * 4 + 2) * 64 + f], p2);
            p3 = fmaf(xv.w, W1s[(k4 * 4 + 3) * 64 + f], p3);
        }
        vsw[w][f] = fmaxf((p0 + p1) + (p2 + p3), 0.f);
        // Phase C: h2h[d][c] = fp16( (sum_k v[k]*W2[k][c]) * dd )
        float p = 0.f;
        const float4* vw4 = (const float4*)vsw[w];
#pragma unroll
        for (int kk4 = 0; kk4 < 4; ++kk4) {
            float4 vv = vw4[G * 4 + kk4];
            p = fmaf(vv.x, W2s[(G * 16 + kk4 * 4 + 0) * 17 + c4], p);
            p = fmaf(vv.y, W2s[(G * 16 + kk4 * 4 + 1) * 17 + c4], p);
            p = fmaf(vv.z, W2s[(G * 16 + kk4 * 4 + 2) * 17 + c4], p);
            p = fmaf(vv.w, W2s[(G * 16 + kk4 * 4 + 3) * 17 + c4], p);
        }
        p += __shfl_xor(p, 16);
        p += __shfl_xor(p, 32);
        if (G == 0) h2h[(size_t)d * 16 + c4] = __float2half(p * dd);
    }
}

// ======== Layer-2 aggregation + b2 + log_softmax ========
// 1 node/wave, 4 waves/block (grid 25000 exact). lane = 16*g + c:
// g = edge slot, c = feature; depth 2 (8 edges in flight).
// h2h is fp16 (3.2MB): L2-resident per XCD -> L2-hit gather latency.

__global__ void k_agg2_lsm(
        const __half* __restrict__ h2h, const int* __restrict__ off,
        const int* __restrict__ csr, const float* __restrict__ dinv,
        const float* __restrict__ b2, float* __restrict__ y, int n) {
    int tid = threadIdx.x;
    int w = tid >> 6, lane = tid & 63, g = lane >> 4, c = lane & 15;
    int d = blockIdx.x * 4 + w;   // grid covers n exactly
    float dd = dinv[d];
    float acc0 = (g == 0) ? __half2float(h2h[(size_t)d * 16 + c]) : 0.f;  // self
    float acc1 = 0.f;
    int j = off[d], je = off[d + 1];
    for (; j + 8 <= je; j += 8) {
        int sA = csr[j + g], sB = csr[j + 4 + g];
        acc0 += __half2float(h2h[(size_t)sA * 16 + c]);
        acc1 += __half2float(h2h[(size_t)sB * 16 + c]);
    }
    for (; j < je; j += 4) {          // covers rem 0..7 fully (<=2 iterations)
        if (j + g < je) {
            int s = csr[j + g];
            acc0 += __half2float(h2h[(size_t)s * 16 + c]);
        }
    }
    float acc = acc0 + acc1;
    acc += __shfl_xor(acc, 16);
    acc += __shfl_xor(acc, 32);
    float v = acc * dd + b2[c];
    float m = v;
#pragma unroll
    for (int o = 1; o < 16; o <<= 1) m = fmaxf(m, __shfl_xor(m, o));
    float ss = expf(v - m);
#pragma unroll
    for (int o = 1; o < 16; o <<= 1) ss += __shfl_xor(ss, o);
    float lse = logf(ss) + m;
    if (g == 0) y[(size_t)d * 16 + c] = v - lse;
}

// ================= launcher =================

extern "C" void kernel_launch(void* const* d_in, const int* in_sizes, int n_in,
                              void* d_out, int out_size, void* d_ws, size_t ws_size,
                              hipStream_t stream) {
    const float* x  = (const float*)d_in[0];
    const int*   ei = (const int*)d_in[1];          // [2, E] row-major
    const float* W1 = (const float*)d_in[2];
    const float* b1 = (const float*)d_in[3];
    const float* W2 = (const float*)d_in[4];
    const float* b2 = (const float*)d_in[5];
    float* y = (float*)d_out;

    const int n = N_NODES;
    const int e = N_EDGES;
    const int* src = ei;
    const int* dst = ei + e;

    // workspace layout (4-byte units); total ~37 MB
    float* ws = (float*)d_ws;
    int*    cnt    = (int*)ws;                   // n
    float*  dinv   = ws + 102400;                // n
    int*    off    = (int*)(ws + 204800);        // n+1
    int*    cursor = (int*)(ws + 307200);        // n
    int*    bsums  = (int*)(ws + 409600);        // <=128
    int*    csr    = (int*)(ws + 410624);        // e
    float*  xs     = ws + 2010624;               // n*64 (25.6MB), 16B-aligned
    __half* h2h    = (__half*)(ws + 8410624);    // n*16 halves (3.2MB)

    const int nb = (n + 1023) / 1024;           // 98

    hipMemsetAsync(cnt, 0, (size_t)n * sizeof(int), stream);
    k_count<<<(e / 4 + 255) / 256, 256, 0, stream>>>(dst, cnt, e);
    k_scanA<<<nb, 256, 0, stream>>>(cnt, off, bsums, dinv, n);
    k_fold <<<n * 16 / 256, 256, 0, stream>>>(x, dinv, xs);          // 6250
    k_scanC<<<(n + 255) / 256, 256, 0, stream>>>(off, cursor, bsums, nb, n);
    k_fill <<<(e / 4 + 255) / 256, 256, 0, stream>>>(src, dst, cursor, csr, e);

    k_agg1    <<<n / 16, 256, 0, stream>>>(xs, off, csr, dinv, W1, W2, b1, h2h, n);  // 6250
    k_agg2_lsm<<<n / 4, 256, 0, stream>>>(h2h, off, csr, dinv, b2, y, n);            // 25000
}

// Round 9
// 277.309 us; speedup vs baseline: 2.1025x; 1.3012x over previous
//
#include <hip/hip_runtime.h>
#include <hip/hip_fp16.h>
#include <math.h>

#define N_NODES 100000
#define N_EDGES 1600000

// ================= CSR build (by dst) =================
// count: rnk[i] = arrival rank of edge i within its dst (atomicAdd return).
// 8-wide: 8 independent atomics in flight per thread, coalesced rank store.

__global__ void k_count(const int* __restrict__ dst, int* __restrict__ cnt,
                        int* __restrict__ rnk, int e) {
    int i = (blockIdx.x * blockDim.x + threadIdx.x) * 8;
    if (i + 8 <= e) {
        int4 dA = *(const int4*)(dst + i);
        int4 dB = *(const int4*)(dst + i + 4);
        int4 rA, rB;
        rA.x = atomicAdd(&cnt[dA.x], 1);
        rA.y = atomicAdd(&cnt[dA.y], 1);
        rA.z = atomicAdd(&cnt[dA.z], 1);
        rA.w = atomicAdd(&cnt[dA.w], 1);
        rB.x = atomicAdd(&cnt[dB.x], 1);
        rB.y = atomicAdd(&cnt[dB.y], 1);
        rB.z = atomicAdd(&cnt[dB.z], 1);
        rB.w = atomicAdd(&cnt[dB.w], 1);
        *(int4*)(rnk + i) = rA;
        *(int4*)(rnk + i + 4) = rB;
    } else {
        for (; i < e; ++i) rnk[i] = atomicAdd(&cnt[dst[i]], 1);
    }
}

// scanA: per-block exclusive scan of 1024 ints (4/thread); block totals -> bsums.
// Also computes dinv = rsqrt(deg+1).
__global__ void k_scanA(const int* __restrict__ cnt, int* __restrict__ off,
                        int* __restrict__ bsums, float* __restrict__ dinv, int n) {
    __shared__ int sd[256];
    int t = threadIdx.x;
    int base = blockIdx.x * 1024 + t * 4;
    int e0 = (base + 0 < n) ? cnt[base + 0] : 0;
    int e1 = (base + 1 < n) ? cnt[base + 1] : 0;
    int e2 = (base + 2 < n) ? cnt[base + 2] : 0;
    int e3 = (base + 3 < n) ? cnt[base + 3] : 0;
    if (base + 0 < n) dinv[base + 0] = rsqrtf((float)e0 + 1.0f);
    if (base + 1 < n) dinv[base + 1] = rsqrtf((float)e1 + 1.0f);
    if (base + 2 < n) dinv[base + 2] = rsqrtf((float)e2 + 1.0f);
    if (base + 3 < n) dinv[base + 3] = rsqrtf((float)e3 + 1.0f);
    int s = e0 + e1 + e2 + e3;
    sd[t] = s;
    __syncthreads();
    for (int o = 1; o < 256; o <<= 1) {
        int v = (t >= o) ? sd[t - o] : 0;
        __syncthreads();
        sd[t] += v;
        __syncthreads();
    }
    int excl = sd[t] - s;
    if (base + 0 < n) off[base + 0] = excl;
    if (base + 1 < n) off[base + 1] = excl + e0;
    if (base + 2 < n) off[base + 2] = excl + e0 + e1;
    if (base + 3 < n) off[base + 3] = excl + e0 + e1 + e2;
    if (t == 0) bsums[blockIdx.x] = sd[255];
}

// scanC: every block redundantly scans bsums (nb<=128) in LDS, then applies the
// prefix to its 256 off entries.
__global__ void k_scanC(int* __restrict__ off, const int* __restrict__ bsums,
                        int nb, int n) {
    __shared__ int sd[128];
    int t = threadIdx.x;
    if (t < 128) sd[t] = (t < nb) ? bsums[t] : 0;
    __syncthreads();
    for (int o = 1; o < 128; o <<= 1) {
        int v = (t >= o && t < 128) ? sd[t - o] : 0;
        __syncthreads();
        if (t < 128) sd[t] += v;
        __syncthreads();
    }
    int i = blockIdx.x * 256 + t;
    if (i < n) {
        int b = i >> 10;
        int add = (b == 0) ? 0 : sd[b - 1];
        off[i] = off[i] + add;
    }
    if (blockIdx.x == 0 && t == 0) off[n] = sd[nb - 1];
}

// fill: atomic-free scatter. pos = off[dst] + rnk; csr[pos] = src.
__global__ void k_fill(const int* __restrict__ src, const int* __restrict__ dst,
                       const int* __restrict__ rnk, const int* __restrict__ off,
                       int* __restrict__ csr, int e) {
    int i = (blockIdx.x * blockDim.x + threadIdx.x) * 4;
    if (i + 4 <= e) {
        int4 s4 = *(const int4*)(src + i);
        int4 d4 = *(const int4*)(dst + i);
        int4 r4 = *(const int4*)(rnk + i);
        csr[off[d4.x] + r4.x] = s4.x;
        csr[off[d4.y] + r4.y] = s4.y;
        csr[off[d4.z] + r4.z] = s4.z;
        csr[off[d4.w] + r4.w] = s4.w;
    } else {
        for (; i < e; ++i) csr[off[dst[i]] + rnk[i]] = src[i];
    }
}

// ======== fold: xs[s][f] = x[s][f] * dinv[s] ========
__global__ void k_fold(const float* __restrict__ x, const float* __restrict__ dinv,
                       float* __restrict__ xs) {
    int t = blockIdx.x * blockDim.x + threadIdx.x;  // float4 index
    float4 v = ((const float4*)x)[t];
    float di = dinv[t >> 4];
    float4 o;
    o.x = v.x * di; o.y = v.y * di; o.z = v.z * di; o.w = v.w * di;
    ((float4*)xs)[t] = o;
}

// ======== Fused layer-1 agg + GEMM1 + relu + GEMM2 ========
// (unchanged from R8 — isolates the CSR-build change)

__global__ void k_agg1(
        const float* __restrict__ xs, const int* __restrict__ off,
        const int* __restrict__ csr, const float* __restrict__ dinv,
        const float* __restrict__ W1, const float* __restrict__ W2,
        const float* __restrict__ b1, __half* __restrict__ h2h, int n) {
    __shared__ float W1s[64 * 64];
    __shared__ float W2s[64 * 17];   // padded
    __shared__ float xsw[4][64];
    __shared__ float vsw[4][64];
    int tid = threadIdx.x;
    {
        const float4* W14 = (const float4*)W1;
        float4* W1s4 = (float4*)W1s;
#pragma unroll
        for (int i = 0; i < 4; ++i) W1s4[tid + 256 * i] = W14[tid + 256 * i];
        for (int i = tid; i < 64 * 16; i += 256) W2s[(i >> 4) * 17 + (i & 15)] = W2[i];
    }
    __syncthreads();  // only block-wide barrier

    int w = tid >> 6, lane = tid & 63;
    int f = lane;
    int G = lane >> 4;
    int c4 = lane & 15;
    float b1f = b1[f];

    int base = blockIdx.x * 16 + w * 4;
#pragma unroll 1
    for (int nn = 0; nn < 4; ++nn) {
        int d = base + nn;    // grid covers n exactly
        float dd = dinv[d];
        float a0 = xs[(size_t)d * 64 + f];   // self term (prefolded)
        float a1 = 0.f, a2 = 0.f, a3 = 0.f;
        int j = off[d], je = off[d + 1];
        int s0 = 0, s1 = 0, s2 = 0, s3 = 0;
        if (j + 4 <= je) { s0 = csr[j]; s1 = csr[j + 1]; s2 = csr[j + 2]; s3 = csr[j + 3]; }
        while (j + 4 <= je) {
            int t0 = s0, t1 = s1, t2 = s2, t3 = s3;
            if (j + 8 <= je) { t0 = csr[j + 4]; t1 = csr[j + 5]; t2 = csr[j + 6]; t3 = csr[j + 7]; }
            a0 += xs[(size_t)s0 * 64 + f];
            a1 += xs[(size_t)s1 * 64 + f];
            a2 += xs[(size_t)s2 * 64 + f];
            a3 += xs[(size_t)s3 * 64 + f];
            s0 = t0; s1 = t1; s2 = t2; s3 = t3;
            j += 4;
        }
        for (; j < je; ++j) {
            int s = csr[j];
            a0 += xs[(size_t)s * 64 + f];
        }
        xsw[w][f] = ((a0 + a1) + (a2 + a3)) * dd;   // same-wave producer
        // Phase B
        float p0 = b1f, p1 = 0.f, p2 = 0.f, p3 = 0.f;
        const float4* xw4 = (const float4*)xsw[w];
#pragma unroll
        for (int k4 = 0; k4 < 16; ++k4) {
            float4 xv = xw4[k4];
            p0 = fmaf(xv.x, W1s[(k4 * 4 + 0) * 64 + f], p0);
            p1 = fmaf(xv.y, W1s[(k4 * 4 + 1) * 64 + f], p1);
            p2 = fmaf(xv.z, W1s[(k4 * 4 + 2) * 64 + f], p2);
            p3 = fmaf(xv.w, W1s[(k4 * 4 + 3) * 64 + f], p3);
        }
        vsw[w][f] = fmaxf((p0 + p1) + (p2 + p3), 0.f);
        // Phase C
        float p = 0.f;
        const float4* vw4 = (const float4*)vsw[w];
#pragma unroll
        for (int kk4 = 0; kk4 < 4; ++kk4) {
            float4 vv = vw4[G * 4 + kk4];
            p = fmaf(vv.x, W2s[(G * 16 + kk4 * 4 + 0) * 17 + c4], p);
            p = fmaf(vv.y, W2s[(G * 16 + kk4 * 4 + 1) * 17 + c4], p);
            p = fmaf(vv.z, W2s[(G * 16 + kk4 * 4 + 2) * 17 + c4], p);
            p = fmaf(vv.w, W2s[(G * 16 + kk4 * 4 + 3) * 17 + c4], p);
        }
        p += __shfl_xor(p, 16);
        p += __shfl_xor(p, 32);
        if (G == 0) h2h[(size_t)d * 16 + c4] = __float2half(p * dd);
    }
}

// ======== Layer-2 aggregation + b2 + log_softmax ========
// (unchanged from R8; h2h fp16, L2-resident)

__global__ void k_agg2_lsm(
        const __half* __restrict__ h2h, const int* __restrict__ off,
        const int* __restrict__ csr, const float* __restrict__ dinv,
        const float* __restrict__ b2, float* __restrict__ y, int n) {
    int tid = threadIdx.x;
    int w = tid >> 6, lane = tid & 63, g = lane >> 4, c = lane & 15;
    int d = blockIdx.x * 4 + w;   // grid covers n exactly
    float dd = dinv[d];
    float acc0 = (g == 0) ? __half2float(h2h[(size_t)d * 16 + c]) : 0.f;  // self
    float acc1 = 0.f;
    int j = off[d], je = off[d + 1];
    for (; j + 8 <= je; j += 8) {
        int sA = csr[j + g], sB = csr[j + 4 + g];
        acc0 += __half2float(h2h[(size_t)sA * 16 + c]);
        acc1 += __half2float(h2h[(size_t)sB * 16 + c]);
    }
    for (; j < je; j += 4) {
        if (j + g < je) {
            int s = csr[j + g];
            acc0 += __half2float(h2h[(size_t)s * 16 + c]);
        }
    }
    float acc = acc0 + acc1;
    acc += __shfl_xor(acc, 16);
    acc += __shfl_xor(acc, 32);
    float v = acc * dd + b2[c];
    float m = v;
#pragma unroll
    for (int o = 1; o < 16; o <<= 1) m = fmaxf(m, __shfl_xor(m, o));
    float ss = expf(v - m);
#pragma unroll
    for (int o = 1; o < 16; o <<= 1) ss += __shfl_xor(ss, o);
    float lse = logf(ss) + m;
    if (g == 0) y[(size_t)d * 16 + c] = v - lse;
}

// ================= launcher =================

extern "C" void kernel_launch(void* const* d_in, const int* in_sizes, int n_in,
                              void* d_out, int out_size, void* d_ws, size_t ws_size,
                              hipStream_t stream) {
    const float* x  = (const float*)d_in[0];
    const int*   ei = (const int*)d_in[1];          // [2, E] row-major
    const float* W1 = (const float*)d_in[2];
    const float* b1 = (const float*)d_in[3];
    const float* W2 = (const float*)d_in[4];
    const float* b2 = (const float*)d_in[5];
    float* y = (float*)d_out;

    const int n = N_NODES;
    const int e = N_EDGES;
    const int* src = ei;
    const int* dst = ei + e;

    // workspace layout (4-byte units); total ~41.6 MB
    float* ws = (float*)d_ws;
    int*    cnt    = (int*)ws;                   // n
    float*  dinv   = ws + 102400;                // n
    int*    off    = (int*)(ws + 204800);        // n+1
    int*    bsums  = (int*)(ws + 307200);        // <=128
    int*    rnk    = (int*)(ws + 409600);        // e
    int*    csr    = (int*)(ws + 2009600);       // e
    float*  xs     = ws + 3609600;               // n*64 (25.6MB), 16B-aligned
    __half* h2h    = (__half*)(ws + 10009600);   // n*16 halves (3.2MB)

    const int nb = (n + 1023) / 1024;           // 98

    hipMemsetAsync(cnt, 0, (size_t)n * sizeof(int), stream);
    k_count<<<(e / 8 + 255) / 256, 256, 0, stream>>>(dst, cnt, rnk, e);
    k_scanA<<<nb, 256, 0, stream>>>(cnt, off, bsums, dinv, n);
    k_fold <<<n * 16 / 256, 256, 0, stream>>>(x, dinv, xs);          // 6250
    k_scanC<<<(n + 255) / 256, 256, 0, stream>>>(off, bsums, nb, n);
    k_fill <<<(e / 4 + 255) / 256, 256, 0, stream>>>(src, dst, rnk, off, csr, e);

    k_agg1    <<<n / 16, 256, 0, stream>>>(xs, off, csr, dinv, W1, W2, b1, h2h, n);  // 6250
    k_agg2_lsm<<<n / 4, 256, 0, stream>>>(h2h, off, csr, dinv, b2, y, n);            // 25000
}